// Round 10
// baseline (83.949 us; speedup 1.0000x reference)
//
#include <hip/hip_runtime.h>
#include <math.h>

#define SL   1024
#define BS   64
#define HID  1024
#define D2   2048            // 2*CELL
#define KCAT 3072            // 2*CELL + HID
#define CELL 1024
#define KS5  16              // K-split for the output GEMM
#define JS5  (KCAT / KS5)    // 192 j per slice
#define TAU  1e-6f           // alignment weight threshold (see R8 theory)

typedef float vfloat4 __attribute__((ext_vector_type(4)));

__device__ __forceinline__ float4 ntload(const float* p) {
    vfloat4 v = __builtin_nontemporal_load(reinterpret_cast<const vfloat4*>(p));
    return make_float4(v.x, v.y, v.z, v.w);
}

__device__ __forceinline__ float waveReduceAdd(float v) {
#pragma unroll
    for (int o = 32; o >= 1; o >>= 1) v += __shfl_xor(v, o, 64);
    return v;
}
__device__ __forceinline__ float waveReduceMax(float v) {
#pragma unroll
    for (int o = 32; o >= 1; o >>= 1) v = fmaxf(v, __shfl_xor(v, o, 64));
    return v;
}

// ---------------------------------------------------------------------------
// K1 (v2): scores[s,b] -> scoresT[b*SL+s]; mask -> maskT[b*SL+s].
// grid: 64 b x 16 slices = 1024 blocks of 256.  Block owns 64 s-rows and
// loops 4 chunks of 16; wave owns 4 rows/chunk (16 nt float4 in flight).
// h_t kept in REGISTERS (4 float4/lane, per wave) -> no LDS, NO BARRIERS:
// waves are fully independent, loads of chunk i+1 overlap reduce of chunk i.
// ---------------------------------------------------------------------------
__global__ __launch_bounds__(256) void k_scores(const float* __restrict__ Wh,
                                                const float* __restrict__ ht,
                                                const float* __restrict__ mask,
                                                float* __restrict__ scoresT,
                                                float* __restrict__ maskT) {
    const int b = blockIdx.x & (BS - 1);
    const int slice = blockIdx.x >> 6;            // 0..15
    const int t = threadIdx.x, wave = t >> 6, lane = t & 63;
    const int sbase = slice * 64;

    if (t < 64)
        maskT[(size_t)b * SL + sbase + t] = mask[(size_t)(sbase + t) * BS + b];

    const float* htb = ht + (size_t)b * HID + lane * 4;
    const float4 h0 = *reinterpret_cast<const float4*>(htb);
    const float4 h1 = *reinterpret_cast<const float4*>(htb + 256);
    const float4 h2 = *reinterpret_cast<const float4*>(htb + 512);
    const float4 h3 = *reinterpret_cast<const float4*>(htb + 768);

#pragma unroll 1
    for (int i = 0; i < 4; ++i) {
        const int s0 = sbase + i * 16 + wave * 4;
        const float* r0 = Wh + ((size_t)(s0 + 0) * BS + b) * HID + lane * 4;
        const float* r1 = Wh + ((size_t)(s0 + 1) * BS + b) * HID + lane * 4;
        const float* r2 = Wh + ((size_t)(s0 + 2) * BS + b) * HID + lane * 4;
        const float* r3 = Wh + ((size_t)(s0 + 3) * BS + b) * HID + lane * 4;

        float4 w[4][4];
#pragma unroll
        for (int k = 0; k < 4; ++k) {
            w[0][k] = ntload(r0 + k * 256);
            w[1][k] = ntload(r1 + k * 256);
            w[2][k] = ntload(r2 + k * 256);
            w[3][k] = ntload(r3 + k * 256);
        }
        float acc0, acc1, acc2, acc3;
        acc0 = fmaf(w[0][0].x, h0.x, fmaf(w[0][0].y, h0.y, fmaf(w[0][0].z, h0.z, w[0][0].w * h0.w)));
        acc1 = fmaf(w[1][0].x, h0.x, fmaf(w[1][0].y, h0.y, fmaf(w[1][0].z, h0.z, w[1][0].w * h0.w)));
        acc2 = fmaf(w[2][0].x, h0.x, fmaf(w[2][0].y, h0.y, fmaf(w[2][0].z, h0.z, w[2][0].w * h0.w)));
        acc3 = fmaf(w[3][0].x, h0.x, fmaf(w[3][0].y, h0.y, fmaf(w[3][0].z, h0.z, w[3][0].w * h0.w)));
        acc0 = fmaf(w[0][1].x, h1.x, fmaf(w[0][1].y, h1.y, fmaf(w[0][1].z, h1.z, fmaf(w[0][1].w, h1.w, acc0))));
        acc1 = fmaf(w[1][1].x, h1.x, fmaf(w[1][1].y, h1.y, fmaf(w[1][1].z, h1.z, fmaf(w[1][1].w, h1.w, acc1))));
        acc2 = fmaf(w[2][1].x, h1.x, fmaf(w[2][1].y, h1.y, fmaf(w[2][1].z, h1.z, fmaf(w[2][1].w, h1.w, acc2))));
        acc3 = fmaf(w[3][1].x, h1.x, fmaf(w[3][1].y, h1.y, fmaf(w[3][1].z, h1.z, fmaf(w[3][1].w, h1.w, acc3))));
        acc0 = fmaf(w[0][2].x, h2.x, fmaf(w[0][2].y, h2.y, fmaf(w[0][2].z, h2.z, fmaf(w[0][2].w, h2.w, acc0))));
        acc1 = fmaf(w[1][2].x, h2.x, fmaf(w[1][2].y, h2.y, fmaf(w[1][2].z, h2.z, fmaf(w[1][2].w, h2.w, acc1))));
        acc2 = fmaf(w[2][2].x, h2.x, fmaf(w[2][2].y, h2.y, fmaf(w[2][2].z, h2.z, fmaf(w[2][2].w, h2.w, acc2))));
        acc3 = fmaf(w[3][2].x, h2.x, fmaf(w[3][2].y, h2.y, fmaf(w[3][2].z, h2.z, fmaf(w[3][2].w, h2.w, acc3))));
        acc0 = fmaf(w[0][3].x, h3.x, fmaf(w[0][3].y, h3.y, fmaf(w[0][3].z, h3.z, fmaf(w[0][3].w, h3.w, acc0))));
        acc1 = fmaf(w[1][3].x, h3.x, fmaf(w[1][3].y, h3.y, fmaf(w[1][3].z, h3.z, fmaf(w[1][3].w, h3.w, acc1))));
        acc2 = fmaf(w[2][3].x, h3.x, fmaf(w[2][3].y, h3.y, fmaf(w[2][3].z, h3.z, fmaf(w[2][3].w, h3.w, acc2))));
        acc3 = fmaf(w[3][3].x, h3.x, fmaf(w[3][3].y, h3.y, fmaf(w[3][3].z, h3.z, fmaf(w[3][3].w, h3.w, acc3))));

        acc0 = waveReduceAdd(acc0);
        acc1 = waveReduceAdd(acc1);
        acc2 = waveReduceAdd(acc2);
        acc3 = waveReduceAdd(acc3);
        if (lane == 0) {
            float* o = scoresT + (size_t)b * SL + s0;
            o[0] = acc0; o[1] = acc1; o[2] = acc2; o[3] = acc3;
        }
    }
}

// ---------------------------------------------------------------------------
// K2 (k_post): per-b block.  Exact masked renormalized softmax -> alignT;
// ballot-compaction (> TAU) in LDS; sparse context directly to ctx.
// ---------------------------------------------------------------------------
__global__ __launch_bounds__(256) void k_post(
    const float* __restrict__ scoresT, const float* __restrict__ maskT,
    const float* __restrict__ hs, float* __restrict__ alignT,
    float* __restrict__ ctx) {
    const int b = blockIdx.x, t = threadIdx.x;
    const int wave = t >> 6, lane = t & 63;
    __shared__ float redm[4], reds[4], redms[4];
    __shared__ float wl[SL];
    __shared__ int   sidx[SL];
    __shared__ float swv[SL];
    __shared__ int   scnt;

    float4 sv = *reinterpret_cast<const float4*>(scoresT + (size_t)b * SL + t * 4);
    float4 mv = *reinterpret_cast<const float4*>(maskT + (size_t)b * SL + t * 4);

    float m = fmaxf(fmaxf(sv.x, sv.y), fmaxf(sv.z, sv.w));
    m = waveReduceMax(m);
    if (lane == 0) redm[wave] = m;
    __syncthreads();
    m = fmaxf(fmaxf(redm[0], redm[1]), fmaxf(redm[2], redm[3]));

    float e0 = __expf(sv.x - m), e1 = __expf(sv.y - m);
    float e2 = __expf(sv.z - m), e3 = __expf(sv.w - m);
    float sum  = e0 + e1 + e2 + e3;
    float msum = e0 * mv.x + e1 * mv.y + e2 * mv.z + e3 * mv.w;
    sum  = waveReduceAdd(sum);
    msum = waveReduceAdd(msum);
    if (lane == 0) { reds[wave] = sum; redms[wave] = msum; }
    __syncthreads();
    sum  = reds[0] + reds[1] + reds[2] + reds[3];
    msum = redms[0] + redms[1] + redms[2] + redms[3];

    const float inv   = 1.0f / sum;
    const float denom = msum * inv + 1e-8f;
    const float scale = inv / denom;

    float4 ao = make_float4(e0 * mv.x * scale, e1 * mv.y * scale,
                            e2 * mv.z * scale, e3 * mv.w * scale);
    *reinterpret_cast<float4*>(alignT + (size_t)b * SL + t * 4) = ao;
    wl[t * 4 + 0] = ao.x; wl[t * 4 + 1] = ao.y;
    wl[t * 4 + 2] = ao.z; wl[t * 4 + 3] = ao.w;
    __syncthreads();

    if (wave == 0) {
        int pos = 0;
        for (int k = 0; k < SL; k += 64) {
            const float w = wl[k + lane];
            const unsigned long long mb = __ballot(w > TAU);
            const int p = __popcll(mb & ((1ull << lane) - 1ull));
            if (w > TAU) {
                sidx[pos + p] = k + lane;
                swv[pos + p]  = w;
            }
            pos += __popcll(mb);
        }
        if (lane == 0) scnt = pos;
    }
    __syncthreads();

    const int n = scnt;
    float4 a0 = make_float4(0.f, 0.f, 0.f, 0.f);
    float4 a1 = make_float4(0.f, 0.f, 0.f, 0.f);
    for (int i = 0; i < n; ++i) {
        const int s   = sidx[i];
        const float w = swv[i];
        const float* hp = hs + ((size_t)s * BS + b) * D2;
        const float4 v0 = ntload(hp + t * 4);
        const float4 v1 = ntload(hp + 1024 + t * 4);
        a0.x = fmaf(w, v0.x, a0.x); a0.y = fmaf(w, v0.y, a0.y);
        a0.z = fmaf(w, v0.z, a0.z); a0.w = fmaf(w, v0.w, a0.w);
        a1.x = fmaf(w, v1.x, a1.x); a1.y = fmaf(w, v1.y, a1.y);
        a1.z = fmaf(w, v1.z, a1.z); a1.w = fmaf(w, v1.w, a1.w);
    }
    *reinterpret_cast<float4*>(ctx + (size_t)b * D2 + t * 4) = a0;
    *reinterpret_cast<float4*>(ctx + (size_t)b * D2 + 1024 + t * 4) = a1;
}

// ---------------------------------------------------------------------------
// K3: split-K GEMM.  grid (CELL/16, KS5), block 256 = 4 waves.
// ---------------------------------------------------------------------------
#define FMA8(acc, r)                                                   \
    acc = fmaf(a[0], wa[r][0].x, acc); acc = fmaf(a[1], wa[r][0].y, acc); \
    acc = fmaf(a[2], wa[r][0].z, acc); acc = fmaf(a[3], wa[r][0].w, acc); \
    acc = fmaf(a[4], wa[r][1].x, acc); acc = fmaf(a[5], wa[r][1].y, acc); \
    acc = fmaf(a[6], wa[r][1].z, acc); acc = fmaf(a[7], wa[r][1].w, acc);

__global__ __launch_bounds__(256) void k_gemm(
    const float* __restrict__ ctx, const float* __restrict__ ht,
    const float* __restrict__ W, float* __restrict__ part5) {
    __shared__ float act[BS * 193];
    const int t = threadIdx.x, wave = t >> 6, lane = t & 63;
    const int jb = blockIdx.y * JS5;
    for (int i2 = t; i2 < BS * (JS5 / 4); i2 += 256) {
        const int row = i2 / (JS5 / 4), c4 = i2 % (JS5 / 4);
        const int jg = jb + c4 * 4;
        const float* src = (jg < D2) ? (ctx + (size_t)row * D2 + jg)
                                     : (ht + (size_t)row * HID + (jg - D2));
        float4 v = *reinterpret_cast<const float4*>(src);
        float* dst = act + row * 193 + c4 * 4;
        dst[0] = v.x; dst[1] = v.y; dst[2] = v.z; dst[3] = v.w;
    }
    __syncthreads();

    int c0 = blockIdx.x * 16 + wave * 4;
    c0 = __builtin_amdgcn_readfirstlane(c0);
    const float* w0 = W + (size_t)c0 * KCAT + jb;
    float acc0 = 0.f, acc1 = 0.f, acc2 = 0.f, acc3 = 0.f;
    for (int j = 0; j < JS5; j += 8) {
        float4 wa[4][2];
#pragma unroll
        for (int rr = 0; rr < 4; ++rr) {
            wa[rr][0] = ntload(w0 + rr * KCAT + j);
            wa[rr][1] = ntload(w0 + rr * KCAT + j + 4);
        }
        float a[8];
#pragma unroll
        for (int k = 0; k < 8; ++k) a[k] = act[lane * 193 + j + k];
        FMA8(acc0, 0) FMA8(acc1, 1) FMA8(acc2, 2) FMA8(acc3, 3)
    }
    float* p = part5 + ((size_t)blockIdx.y * CELL + c0) * BS + lane;
    p[0 * BS] = acc0; p[1 * BS] = acc1; p[2 * BS] = acc2; p[3 * BS] = acc3;
}

// ---------------------------------------------------------------------------
// K4: out[b][c] = tanh(bias[c] + sum_ks part5[ks][c][b]).
// ---------------------------------------------------------------------------
__global__ __launch_bounds__(256) void k_finish(
    const float* __restrict__ part5, const float* __restrict__ bias,
    float* __restrict__ out) {
    __shared__ float tile[16][65];
    const int ct = blockIdx.x;
    const int t = threadIdx.x, b = t & 63, cl = t >> 6;
    float acc[4] = {0.f, 0.f, 0.f, 0.f};
#pragma unroll
    for (int ks = 0; ks < KS5; ++ks) {
#pragma unroll
        for (int i = 0; i < 4; ++i) {
            const int c = ct * 16 + cl * 4 + i;
            acc[i] += part5[((size_t)ks * CELL + c) * BS + b];
        }
    }
#pragma unroll
    for (int i = 0; i < 4; ++i) {
        const int c_local = cl * 4 + i;
        tile[c_local][b] = tanhf(acc[i] + bias[ct * 16 + c_local]);
    }
    __syncthreads();
    const int c_w = t & 15, bq = t >> 4;
#pragma unroll
    for (int i = 0; i < 4; ++i) {
        const int b_w = bq + 16 * i;
        out[(size_t)b_w * CELL + ct * 16 + c_w] = tile[c_w][b_w];
    }
}

// ---------------------------------------------------------------------------
extern "C" void kernel_launch(void* const* d_in, const int* in_sizes, int n_in,
                              void* d_out, int out_size, void* d_ws, size_t ws_size,
                              hipStream_t stream) {
    const float* Wh   = (const float*)d_in[0];   // (SL, BS, HID)
    const float* ht   = (const float*)d_in[1];   // (BS, HID)
    const float* mask = (const float*)d_in[2];   // (SL, BS)
    const float* hs   = (const float*)d_in[3];   // (SL, BS, D2)
    const float* W    = (const float*)d_in[4];   // (CELL, KCAT)
    const float* bias = (const float*)d_in[5];   // (CELL,)

    float* out    = (float*)d_out;
    float* htilde = out;                       // (BS, CELL)
    float* alignT = out + (size_t)BS * CELL;   // (BS, SL)

    // workspace (floats): scoresT | maskT | ctx | part5
    float* ws      = (float*)d_ws;
    float* scoresT = ws;
    float* maskT   = scoresT + (size_t)BS * SL;
    float* ctx     = maskT + (size_t)BS * SL;
    float* part5   = ctx + (size_t)BS * D2;

    k_scores<<<BS * 16, 256, 0, stream>>>(Wh, ht, mask, scoresT, maskT);
    k_post<<<BS, 256, 0, stream>>>(scoresT, maskT, hs, alignT, ctx);
    dim3 g5(CELL / 16, KS5);
    k_gemm<<<g5, 256, 0, stream>>>(ctx, ht, W, part5);
    k_finish<<<BS, 256, 0, stream>>>(part5, bias, htilde);
}

// Round 11
// 77.964 us; speedup vs baseline: 1.0768x; 1.0768x over previous
//
#include <hip/hip_runtime.h>
#include <math.h>

#define SL   1024
#define BS   64
#define HID  1024
#define D2   2048            // 2*CELL
#define KCAT 3072            // 2*CELL + HID
#define CELL 1024
#define KS5  16              // K-split for the output GEMM
#define JS5  (KCAT / KS5)    // 192 j per slice
#define TAU  1e-6f           // alignment weight threshold (see R8 theory)

typedef float vfloat4 __attribute__((ext_vector_type(4)));

__device__ __forceinline__ float4 ntload(const float* p) {
    vfloat4 v = __builtin_nontemporal_load(reinterpret_cast<const vfloat4*>(p));
    return make_float4(v.x, v.y, v.z, v.w);
}

__device__ __forceinline__ float waveReduceAdd(float v) {
#pragma unroll
    for (int o = 32; o >= 1; o >>= 1) v += __shfl_xor(v, o, 64);
    return v;
}
__device__ __forceinline__ float waveReduceMax(float v) {
#pragma unroll
    for (int o = 32; o >= 1; o >>= 1) v = fmaxf(v, __shfl_xor(v, o, 64));
    return v;
}

// ---------------------------------------------------------------------------
// K1 (v3, "sequential16"): scores -> scoresT[b*SL+s]; mask -> maskT[b*SL+s].
// grid: 4096 blocks of 256.  Block owns (4 s) x (4 b): bg = blk & 15,
// sg = blk >> 4.  Wave w takes b = bg*4+w for ALL 4 s -> each of the
// block's 4 volleys covers 16 KB CONTIGUOUS (4 consecutive b), and
// consecutive blockIdx extend the run (consecutive bg).  16 nt float4
// loads in flight per wave; h_t in registers; no LDS, no barriers.
// Only k_scores differs from R10 — clean A/B on volley contiguity.
// ---------------------------------------------------------------------------
__global__ __launch_bounds__(256) void k_scores(const float* __restrict__ Wh,
                                                const float* __restrict__ ht,
                                                const float* __restrict__ mask,
                                                float* __restrict__ scoresT,
                                                float* __restrict__ maskT) {
    const int bg = blockIdx.x & 15;               // 0..15
    const int sg = blockIdx.x >> 4;               // 0..255
    const int t = threadIdx.x, wave = t >> 6, lane = t & 63;
    const int s0 = sg * 4;
    const int b0 = bg * 4;
    const int b  = b0 + wave;

    if (t < 16) {
        const int s_i = t >> 2, b_i = t & 3;
        maskT[(size_t)(b0 + b_i) * SL + s0 + s_i] =
            mask[(size_t)(s0 + s_i) * BS + b0 + b_i];
    }

    const float* htb = ht + (size_t)b * HID + lane * 4;
    const float4 h0 = *reinterpret_cast<const float4*>(htb);
    const float4 h1 = *reinterpret_cast<const float4*>(htb + 256);
    const float4 h2 = *reinterpret_cast<const float4*>(htb + 512);
    const float4 h3 = *reinterpret_cast<const float4*>(htb + 768);

    const float* r0 = Wh + ((size_t)(s0 + 0) * BS + b) * HID + lane * 4;
    const float* r1 = Wh + ((size_t)(s0 + 1) * BS + b) * HID + lane * 4;
    const float* r2 = Wh + ((size_t)(s0 + 2) * BS + b) * HID + lane * 4;
    const float* r3 = Wh + ((size_t)(s0 + 3) * BS + b) * HID + lane * 4;

    float4 w[4][4];
#pragma unroll
    for (int k = 0; k < 4; ++k) {
        w[0][k] = ntload(r0 + k * 256);
        w[1][k] = ntload(r1 + k * 256);
        w[2][k] = ntload(r2 + k * 256);
        w[3][k] = ntload(r3 + k * 256);
    }
    float acc0, acc1, acc2, acc3;
    acc0 = fmaf(w[0][0].x, h0.x, fmaf(w[0][0].y, h0.y, fmaf(w[0][0].z, h0.z, w[0][0].w * h0.w)));
    acc1 = fmaf(w[1][0].x, h0.x, fmaf(w[1][0].y, h0.y, fmaf(w[1][0].z, h0.z, w[1][0].w * h0.w)));
    acc2 = fmaf(w[2][0].x, h0.x, fmaf(w[2][0].y, h0.y, fmaf(w[2][0].z, h0.z, w[2][0].w * h0.w)));
    acc3 = fmaf(w[3][0].x, h0.x, fmaf(w[3][0].y, h0.y, fmaf(w[3][0].z, h0.z, w[3][0].w * h0.w)));
    acc0 = fmaf(w[0][1].x, h1.x, fmaf(w[0][1].y, h1.y, fmaf(w[0][1].z, h1.z, fmaf(w[0][1].w, h1.w, acc0))));
    acc1 = fmaf(w[1][1].x, h1.x, fmaf(w[1][1].y, h1.y, fmaf(w[1][1].z, h1.z, fmaf(w[1][1].w, h1.w, acc1))));
    acc2 = fmaf(w[2][1].x, h1.x, fmaf(w[2][1].y, h1.y, fmaf(w[2][1].z, h1.z, fmaf(w[2][1].w, h1.w, acc2))));
    acc3 = fmaf(w[3][1].x, h1.x, fmaf(w[3][1].y, h1.y, fmaf(w[3][1].z, h1.z, fmaf(w[3][1].w, h1.w, acc3))));
    acc0 = fmaf(w[0][2].x, h2.x, fmaf(w[0][2].y, h2.y, fmaf(w[0][2].z, h2.z, fmaf(w[0][2].w, h2.w, acc0))));
    acc1 = fmaf(w[1][2].x, h2.x, fmaf(w[1][2].y, h2.y, fmaf(w[1][2].z, h2.z, fmaf(w[1][2].w, h2.w, acc1))));
    acc2 = fmaf(w[2][2].x, h2.x, fmaf(w[2][2].y, h2.y, fmaf(w[2][2].z, h2.z, fmaf(w[2][2].w, h2.w, acc2))));
    acc3 = fmaf(w[3][2].x, h2.x, fmaf(w[3][2].y, h2.y, fmaf(w[3][2].z, h2.z, fmaf(w[3][2].w, h2.w, acc3))));
    acc0 = fmaf(w[0][3].x, h3.x, fmaf(w[0][3].y, h3.y, fmaf(w[0][3].z, h3.z, fmaf(w[0][3].w, h3.w, acc0))));
    acc1 = fmaf(w[1][3].x, h3.x, fmaf(w[1][3].y, h3.y, fmaf(w[1][3].z, h3.z, fmaf(w[1][3].w, h3.w, acc1))));
    acc2 = fmaf(w[2][3].x, h3.x, fmaf(w[2][3].y, h3.y, fmaf(w[2][3].z, h3.z, fmaf(w[2][3].w, h3.w, acc2))));
    acc3 = fmaf(w[3][3].x, h3.x, fmaf(w[3][3].y, h3.y, fmaf(w[3][3].z, h3.z, fmaf(w[3][3].w, h3.w, acc3))));

    acc0 = waveReduceAdd(acc0);
    acc1 = waveReduceAdd(acc1);
    acc2 = waveReduceAdd(acc2);
    acc3 = waveReduceAdd(acc3);
    if (lane == 0) {
        float* o = scoresT + (size_t)b * SL + s0;
        o[0] = acc0; o[1] = acc1; o[2] = acc2; o[3] = acc3;
    }
}

// ---------------------------------------------------------------------------
// K2 (k_post): per-b block.  Exact masked renormalized softmax -> alignT;
// ballot-compaction (> TAU) in LDS; sparse context directly to ctx.
// ---------------------------------------------------------------------------
__global__ __launch_bounds__(256) void k_post(
    const float* __restrict__ scoresT, const float* __restrict__ maskT,
    const float* __restrict__ hs, float* __restrict__ alignT,
    float* __restrict__ ctx) {
    const int b = blockIdx.x, t = threadIdx.x;
    const int wave = t >> 6, lane = t & 63;
    __shared__ float redm[4], reds[4], redms[4];
    __shared__ float wl[SL];
    __shared__ int   sidx[SL];
    __shared__ float swv[SL];
    __shared__ int   scnt;

    float4 sv = *reinterpret_cast<const float4*>(scoresT + (size_t)b * SL + t * 4);
    float4 mv = *reinterpret_cast<const float4*>(maskT + (size_t)b * SL + t * 4);

    float m = fmaxf(fmaxf(sv.x, sv.y), fmaxf(sv.z, sv.w));
    m = waveReduceMax(m);
    if (lane == 0) redm[wave] = m;
    __syncthreads();
    m = fmaxf(fmaxf(redm[0], redm[1]), fmaxf(redm[2], redm[3]));

    float e0 = __expf(sv.x - m), e1 = __expf(sv.y - m);
    float e2 = __expf(sv.z - m), e3 = __expf(sv.w - m);
    float sum  = e0 + e1 + e2 + e3;
    float msum = e0 * mv.x + e1 * mv.y + e2 * mv.z + e3 * mv.w;
    sum  = waveReduceAdd(sum);
    msum = waveReduceAdd(msum);
    if (lane == 0) { reds[wave] = sum; redms[wave] = msum; }
    __syncthreads();
    sum  = reds[0] + reds[1] + reds[2] + reds[3];
    msum = redms[0] + redms[1] + redms[2] + redms[3];

    const float inv   = 1.0f / sum;
    const float denom = msum * inv + 1e-8f;
    const float scale = inv / denom;

    float4 ao = make_float4(e0 * mv.x * scale, e1 * mv.y * scale,
                            e2 * mv.z * scale, e3 * mv.w * scale);
    *reinterpret_cast<float4*>(alignT + (size_t)b * SL + t * 4) = ao;
    wl[t * 4 + 0] = ao.x; wl[t * 4 + 1] = ao.y;
    wl[t * 4 + 2] = ao.z; wl[t * 4 + 3] = ao.w;
    __syncthreads();

    if (wave == 0) {
        int pos = 0;
        for (int k = 0; k < SL; k += 64) {
            const float w = wl[k + lane];
            const unsigned long long mb = __ballot(w > TAU);
            const int p = __popcll(mb & ((1ull << lane) - 1ull));
            if (w > TAU) {
                sidx[pos + p] = k + lane;
                swv[pos + p]  = w;
            }
            pos += __popcll(mb);
        }
        if (lane == 0) scnt = pos;
    }
    __syncthreads();

    const int n = scnt;
    float4 a0 = make_float4(0.f, 0.f, 0.f, 0.f);
    float4 a1 = make_float4(0.f, 0.f, 0.f, 0.f);
    for (int i = 0; i < n; ++i) {
        const int s   = sidx[i];
        const float w = swv[i];
        const float* hp = hs + ((size_t)s * BS + b) * D2;
        const float4 v0 = ntload(hp + t * 4);
        const float4 v1 = ntload(hp + 1024 + t * 4);
        a0.x = fmaf(w, v0.x, a0.x); a0.y = fmaf(w, v0.y, a0.y);
        a0.z = fmaf(w, v0.z, a0.z); a0.w = fmaf(w, v0.w, a0.w);
        a1.x = fmaf(w, v1.x, a1.x); a1.y = fmaf(w, v1.y, a1.y);
        a1.z = fmaf(w, v1.z, a1.z); a1.w = fmaf(w, v1.w, a1.w);
    }
    *reinterpret_cast<float4*>(ctx + (size_t)b * D2 + t * 4) = a0;
    *reinterpret_cast<float4*>(ctx + (size_t)b * D2 + 1024 + t * 4) = a1;
}

// ---------------------------------------------------------------------------
// K3: split-K GEMM.  grid (CELL/16, KS5), block 256 = 4 waves.
// ---------------------------------------------------------------------------
#define FMA8(acc, r)                                                   \
    acc = fmaf(a[0], wa[r][0].x, acc); acc = fmaf(a[1], wa[r][0].y, acc); \
    acc = fmaf(a[2], wa[r][0].z, acc); acc = fmaf(a[3], wa[r][0].w, acc); \
    acc = fmaf(a[4], wa[r][1].x, acc); acc = fmaf(a[5], wa[r][1].y, acc); \
    acc = fmaf(a[6], wa[r][1].z, acc); acc = fmaf(a[7], wa[r][1].w, acc);

__global__ __launch_bounds__(256) void k_gemm(
    const float* __restrict__ ctx, const float* __restrict__ ht,
    const float* __restrict__ W, float* __restrict__ part5) {
    __shared__ float act[BS * 193];
    const int t = threadIdx.x, wave = t >> 6, lane = t & 63;
    const int jb = blockIdx.y * JS5;
    for (int i2 = t; i2 < BS * (JS5 / 4); i2 += 256) {
        const int row = i2 / (JS5 / 4), c4 = i2 % (JS5 / 4);
        const int jg = jb + c4 * 4;
        const float* src = (jg < D2) ? (ctx + (size_t)row * D2 + jg)
                                     : (ht + (size_t)row * HID + (jg - D2));
        float4 v = *reinterpret_cast<const float4*>(src);
        float* dst = act + row * 193 + c4 * 4;
        dst[0] = v.x; dst[1] = v.y; dst[2] = v.z; dst[3] = v.w;
    }
    __syncthreads();

    int c0 = blockIdx.x * 16 + wave * 4;
    c0 = __builtin_amdgcn_readfirstlane(c0);
    const float* w0 = W + (size_t)c0 * KCAT + jb;
    float acc0 = 0.f, acc1 = 0.f, acc2 = 0.f, acc3 = 0.f;
    for (int j = 0; j < JS5; j += 8) {
        float4 wa[4][2];
#pragma unroll
        for (int rr = 0; rr < 4; ++rr) {
            wa[rr][0] = ntload(w0 + rr * KCAT + j);
            wa[rr][1] = ntload(w0 + rr * KCAT + j + 4);
        }
        float a[8];
#pragma unroll
        for (int k = 0; k < 8; ++k) a[k] = act[lane * 193 + j + k];
        FMA8(acc0, 0) FMA8(acc1, 1) FMA8(acc2, 2) FMA8(acc3, 3)
    }
    float* p = part5 + ((size_t)blockIdx.y * CELL + c0) * BS + lane;
    p[0 * BS] = acc0; p[1 * BS] = acc1; p[2 * BS] = acc2; p[3 * BS] = acc3;
}

// ---------------------------------------------------------------------------
// K4: out[b][c] = tanh(bias[c] + sum_ks part5[ks][c][b]).
// ---------------------------------------------------------------------------
__global__ __launch_bounds__(256) void k_finish(
    const float* __restrict__ part5, const float* __restrict__ bias,
    float* __restrict__ out) {
    __shared__ float tile[16][65];
    const int ct = blockIdx.x;
    const int t = threadIdx.x, b = t & 63, cl = t >> 6;
    float acc[4] = {0.f, 0.f, 0.f, 0.f};
#pragma unroll
    for (int ks = 0; ks < KS5; ++ks) {
#pragma unroll
        for (int i = 0; i < 4; ++i) {
            const int c = ct * 16 + cl * 4 + i;
            acc[i] += part5[((size_t)ks * CELL + c) * BS + b];
        }
    }
#pragma unroll
    for (int i = 0; i < 4; ++i) {
        const int c_local = cl * 4 + i;
        tile[c_local][b] = tanhf(acc[i] + bias[ct * 16 + c_local]);
    }
    __syncthreads();
    const int c_w = t & 15, bq = t >> 4;
#pragma unroll
    for (int i = 0; i < 4; ++i) {
        const int b_w = bq + 16 * i;
        out[(size_t)b_w * CELL + ct * 16 + c_w] = tile[c_w][b_w];
    }
}

// ---------------------------------------------------------------------------
extern "C" void kernel_launch(void* const* d_in, const int* in_sizes, int n_in,
                              void* d_out, int out_size, void* d_ws, size_t ws_size,
                              hipStream_t stream) {
    const float* Wh   = (const float*)d_in[0];   // (SL, BS, HID)
    const float* ht   = (const float*)d_in[1];   // (BS, HID)
    const float* mask = (const float*)d_in[2];   // (SL, BS)
    const float* hs   = (const float*)d_in[3];   // (SL, BS, D2)
    const float* W    = (const float*)d_in[4];   // (CELL, KCAT)
    const float* bias = (const float*)d_in[5];   // (CELL,)

    float* out    = (float*)d_out;
    float* htilde = out;                       // (BS, CELL)
    float* alignT = out + (size_t)BS * CELL;   // (BS, SL)

    // workspace (floats): scoresT | maskT | ctx | part5
    float* ws      = (float*)d_ws;
    float* scoresT = ws;
    float* maskT   = scoresT + (size_t)BS * SL;
    float* ctx     = maskT + (size_t)BS * SL;
    float* part5   = ctx + (size_t)BS * D2;

    k_scores<<<(SL / 4) * (BS / 4), 256, 0, stream>>>(Wh, ht, mask, scoresT, maskT);
    k_post<<<BS, 256, 0, stream>>>(scoresT, maskT, hs, alignT, ctx);
    dim3 g5(CELL / 16, KS5);
    k_gemm<<<g5, 256, 0, stream>>>(ctx, ht, W, part5);
    k_finish<<<BS, 256, 0, stream>>>(part5, bias, htilde);
}